// Round 1
// baseline (215282.422 us; speedup 1.0000x reference)
//
#include <hip/hip_runtime.h>
#include <hip/hip_bf16.h>
#include <hip/hip_cooperative_groups.h>

namespace cg = cooperative_groups;

// Problem constants
#define NLAYERS 4
#define NHID    512
#define NINP    128
#define TT      1024
#define BB      32

typedef unsigned short u16;
typedef short bf16x8 __attribute__((ext_vector_type(8)));   // 8 bf16 = 4 VGPRs (MFMA A/B frag)
typedef float f32x16 __attribute__((ext_vector_type(16)));  // MFMA 32x32 C/D frag

__device__ __forceinline__ u16 f2bf(float x){
    union { float f; unsigned u; } v; v.f = x;
    unsigned r = v.u + 0x7fffu + ((v.u >> 16) & 1u);   // RNE
    return (u16)(r >> 16);
}
__device__ __forceinline__ float bf2f(u16 u){
    union { unsigned u; float f; } v; v.u = ((unsigned)u) << 16;
    return v.f;
}
__device__ __forceinline__ float sigf(float x){ return 1.0f/(1.0f + __expf(-x)); }

// ---------------------------------------------------------------------------
// Input projection: xp[row][h] = sum_i x[row][i]*lin_w[h][i] + lin_b[h], bf16 out
// row = t*32+b (32768 rows), K=128, N=512. One block = 16 rows x 512 cols.
// ---------------------------------------------------------------------------
__global__ __launch_bounds__(256) void k_xp(const float* __restrict__ x,
                                            const float* __restrict__ lin_w,
                                            const float* __restrict__ lin_b,
                                            u16* __restrict__ xp)
{
    __shared__ float xl[16][128];
    const int rowbase = blockIdx.x * 16;
    const int t = threadIdx.x;
    for (int idx = t; idx < 16*128; idx += 256) {
        int r = idx >> 7, i = idx & 127;
        xl[r][i] = x[(rowbase + r)*128 + i];
    }
    __syncthreads();
    const int c0 = t;              // handles cols c0 and c0+256
    float acc0[16], acc1[16];
    #pragma unroll
    for (int r=0;r<16;r++){ acc0[r]=0.f; acc1[r]=0.f; }
    for (int k=0;k<128;k++){
        float w0 = lin_w[c0*128+k];
        float w1 = lin_w[(c0+256)*128+k];
        #pragma unroll
        for (int r=0;r<16;r++){
            float xv = xl[r][k];
            acc0[r] += xv*w0;
            acc1[r] += xv*w1;
        }
    }
    float b0 = lin_b[c0], b1 = lin_b[c0+256];
    #pragma unroll
    for (int r=0;r<16;r++){
        xp[(rowbase+r)*512 + c0]       = f2bf(acc0[r] + b0);
        xp[(rowbase+r)*512 + c0 + 256] = f2bf(acc1[r] + b1);
    }
}

// fp32 -> bf16 bulk convert (n multiple of 4)
__global__ __launch_bounds__(256) void k_cvt(const float* __restrict__ src,
                                             u16* __restrict__ dst, int n)
{
    int i = (blockIdx.x*256 + threadIdx.x)*4;
    if (i < n){
        float4 v = *reinterpret_cast<const float4*>(src + i);
        ushort4 o;
        o.x = f2bf(v.x); o.y = f2bf(v.y); o.z = f2bf(v.z); o.w = f2bf(v.w);
        *reinterpret_cast<ushort4*>(dst + i) = o;
    }
}

// ---------------------------------------------------------------------------
// Persistent cooperative recurrent kernel. 256 blocks x 256 threads.
// Per step: A (gh/hx/inp0) -> B (GU = hx @ U^T, MFMA) -> C_i x4 (W GEMM + LSTM).
// ---------------------------------------------------------------------------
__global__ __launch_bounds__(256, 1) void k_rnn(
    const u16*  __restrict__ xp,      // [32768][512] bf16
    const u16*  __restrict__ Wb,      // [4][2048][512] bf16
    const u16*  __restrict__ Ub,      // [4][2048][2048] bf16
    const float* __restrict__ Gp,     // [4][512]
    const float* __restrict__ mask_u, // [4][32][512]
    const float* __restrict__ mask_w, // [4][32][512]
    const float* __restrict__ h0,
    const float* __restrict__ c0,
    float* __restrict__ h,            // [4][32][512] ws
    float* __restrict__ c,            // [4][32][512] ws
    u16*  __restrict__ hx,            // [32][2048] bf16 ws
    u16*  __restrict__ inp,           // [2][32][512] bf16 ws (layer-parity dbuf)
    float* __restrict__ GU,           // [4][32][2048] ws
    float* __restrict__ out)          // d_out: hT | cT | gates[l][b][t]
{
    cg::grid_group grid = cg::this_grid();
    const int blk  = blockIdx.x;
    const int tid  = threadIdx.x;
    const int lane = tid & 63;
    const int wave = tid >> 6;

    __shared__ float smem[4160];

    // init state
    {
        int idx = blk*256 + tid;      // exactly 65536 threads
        h[idx] = h0[idx];
        c[idx] = c0[idx];
    }
    grid.sync();

    for (int t = 0; t < TT; ++t){
        // ---------------- Phase A ----------------
        if (blk < 128){
            int l = blk >> 5, b = blk & 31;
            const float* hp = h      + (l*32+b)*512;
            const float* mp = mask_u + (l*32+b)*512;
            const float* gp = Gp     + l*512;
            float hm0 = hp[tid]     * mp[tid];
            float hm1 = hp[tid+256] * mp[tid+256];
            float p = hm0*gp[tid] + hm1*gp[tid+256];
            #pragma unroll
            for (int off=32; off>0; off>>=1) p += __shfl_down(p, off);
            if (lane==0) smem[wave] = p;
            __syncthreads();
            if (tid==0){
                float s  = smem[0]+smem[1]+smem[2]+smem[3];
                float gh = sigf(s);
                smem[4] = gh;
                out[2*65536 + (l*32+b)*1024 + t] = gh;    // gates[l][b][t]
            }
            __syncthreads();
            float gh = smem[4];
            u16* hxp = hx + b*2048 + l*512;
            hxp[tid]     = f2bf(gh*hm0);
            hxp[tid+256] = f2bf(gh*hm1);
        } else if (blk < 144){
            // inp0 = xp[t] * mask_w[0]  -> inp buffer 0
            int base = (blk-128)*1024 + tid;
            #pragma unroll
            for (int r=0;r<4;r++){
                int idx = base + r*256;            // 16*1024 = 16384 elems
                int b = idx >> 9, k = idx & 511;
                float xv = bf2f(xp[(t*32+b)*512 + k]);
                inp[b*512 + k] = f2bf(xv * mask_w[b*512 + k]);
            }
        }
        grid.sync();

        // ---------------- Phase B: GU[l] = hx @ U[l]^T ----------------
        {
            int l     = blk >> 6;
            int obase = (blk & 63) * 32;
            const u16* urow = Ub + ((size_t)(l*2048 + obase + (lane&31)))*2048;
            const u16* arow = hx + (lane&31)*2048;
            const int khalf = (lane>>5)*8;
            const int k0 = wave*512 + khalf;
            f32x16 acc;
            #pragma unroll
            for (int r=0;r<16;r++) acc[r] = 0.f;
            #pragma unroll 4
            for (int m=0;m<32;m++){
                int kk = k0 + m*16;
                bf16x8 a  = *reinterpret_cast<const bf16x8*>(arow + kk);
                bf16x8 bv = *reinterpret_cast<const bf16x8*>(urow + kk);
                acc = __builtin_amdgcn_mfma_f32_32x32x16_bf16(a, bv, acc, 0, 0, 0);
            }
            #pragma unroll
            for (int r=0;r<16;r++) smem[wave*1024 + r*64 + lane] = acc[r];
            __syncthreads();
            for (int pos = tid; pos < 1024; pos += 256){
                float s = smem[pos] + smem[1024+pos] + smem[2048+pos] + smem[3072+pos];
                int r = pos >> 6, ln = pos & 63;
                int row = (r&3) + 8*(r>>2) + 4*(ln>>5);     // verified C/D mapping
                int col = obase + (ln&31);
                GU[(l*32+row)*2048 + col] = s;
            }
        }
        grid.sync();

        // ---------------- Phase C: layer chain ----------------
        for (int i=0; i<NLAYERS; ++i){
            if (blk < 16){
                const int hbase = blk*32;
                const int o     = wave*512 + hbase + (lane&31);  // wave = gate index
                const u16* wrow = Wb  + ((size_t)(i*2048 + o))*512;
                const u16* arow = inp + (i&1)*16384 + (lane&31)*512;
                const int khalf = (lane>>5)*8;
                f32x16 acc;
                #pragma unroll
                for (int r=0;r<16;r++) acc[r] = 0.f;
                #pragma unroll 4
                for (int m=0;m<32;m++){
                    int kk = khalf + m*16;
                    bf16x8 a  = *reinterpret_cast<const bf16x8*>(arow + kk);
                    bf16x8 bv = *reinterpret_cast<const bf16x8*>(wrow + kk);
                    acc = __builtin_amdgcn_mfma_f32_32x32x16_bf16(a, bv, acc, 0, 0, 0);
                }
                #pragma unroll
                for (int r=0;r<16;r++){
                    int row = (r&3) + 8*(r>>2) + 4*(lane>>5);
                    acc[r] += GU[(i*32+row)*2048 + o];
                    smem[wave*1024 + r*64 + lane] = acc[r];
                }
                __syncthreads();
                for (int pos = tid; pos < 1024; pos += 256){
                    int r = pos >> 6, ln = pos & 63;
                    int b  = (r&3) + 8*(r>>2) + 4*(ln>>5);
                    int hh = hbase + (ln&31);
                    float ii = smem[pos];
                    float ff = smem[1024+pos];
                    float gg = smem[2048+pos];
                    float oo = smem[3072+pos];
                    int cidx = (i*32+b)*512 + hh;
                    float cy = sigf(ff)*c[cidx] + sigf(ii)*tanhf(gg);
                    float hy = sigf(oo)*tanhf(cy);
                    c[cidx] = cy;
                    h[cidx] = hy;
                    if (i < 3)
                        inp[((i+1)&1)*16384 + b*512 + hh] =
                            f2bf(hy * mask_w[(i+1)*16384 + b*512 + hh]);
                }
                __syncthreads();
            }
            grid.sync();
        }
    }

    // final hT, cT
    {
        int idx = blk*256 + tid;
        out[idx]         = h[idx];
        out[65536 + idx] = c[idx];
    }
}

// ---------------------------------------------------------------------------
extern "C" void kernel_launch(void* const* d_in, const int* in_sizes, int n_in,
                              void* d_out, int out_size, void* d_ws, size_t ws_size,
                              hipStream_t stream)
{
    const float* x      = (const float*)d_in[0];
    const float* lin_w  = (const float*)d_in[1];
    const float* lin_b  = (const float*)d_in[2];
    const float* W      = (const float*)d_in[3];
    const float* U      = (const float*)d_in[4];
    const float* Gp     = (const float*)d_in[5];
    const float* mask_u = (const float*)d_in[6];
    const float* mask_w = (const float*)d_in[7];
    const float* h0     = (const float*)d_in[8];
    const float* c0     = (const float*)d_in[9];
    float* out = (float*)d_out;

    char* ws = (char*)d_ws;
    size_t off = 0;
    auto alloc = [&](size_t bytes) -> void* {
        void* p = ws + off;
        off = (off + bytes + 255) & ~(size_t)255;
        return p;
    };
    u16*   xp  = (u16*)  alloc(32768ull*512*2);       // 33.6 MB
    u16*   Ub  = (u16*)  alloc(4ull*2048*2048*2);     // 33.6 MB
    u16*   Wb  = (u16*)  alloc(4ull*2048*512*2);      //  8.4 MB
    float* h   = (float*)alloc(65536ull*4);
    float* c   = (float*)alloc(65536ull*4);
    u16*   hx  = (u16*)  alloc(32ull*2048*2);
    u16*   inp = (u16*)  alloc(2ull*32*512*2);
    float* GU  = (float*)alloc(4ull*32*2048*4);

    hipLaunchKernelGGL(k_xp,  dim3(2048),  dim3(256), 0, stream, x, lin_w, lin_b, xp);
    hipLaunchKernelGGL(k_cvt, dim3(16384), dim3(256), 0, stream, U, Ub, 16777216);
    hipLaunchKernelGGL(k_cvt, dim3(4096),  dim3(256), 0, stream, W, Wb, 4194304);

    void* args[] = { &xp, &Wb, &Ub, &Gp, &mask_u, &mask_w, &h0, &c0,
                     &h, &c, &hx, &inp, &GU, &out };
    hipLaunchCooperativeKernel(reinterpret_cast<void*>(k_rnn),
                               dim3(256), dim3(256), args, 0, stream);
}

// Round 2
// 123923.828 us; speedup vs baseline: 1.7372x; 1.7372x over previous
//
#include <hip/hip_runtime.h>
#include <hip/hip_bf16.h>

// Problem constants
#define NLAYERS 4
#define NHID    512
#define NINP    128
#define TT      1024
#define BB      32

typedef unsigned short u16;
typedef short bf16x8 __attribute__((ext_vector_type(8)));   // 8 bf16 = 4 VGPRs (MFMA A/B frag)
typedef float f32x16 __attribute__((ext_vector_type(16)));  // MFMA 32x32 C/D frag

__device__ __forceinline__ u16 f2bf(float x){
    union { float f; unsigned u; } v; v.f = x;
    unsigned r = v.u + 0x7fffu + ((v.u >> 16) & 1u);   // RNE
    return (u16)(r >> 16);
}
__device__ __forceinline__ float bf2f(u16 u){
    union { unsigned u; float f; } v; v.u = ((unsigned)u) << 16;
    return v.f;
}
__device__ __forceinline__ float sigf(float x){ return 1.0f/(1.0f + __expf(-x)); }

// Lean device-scope barrier: monotonic counter, one arriver per block.
// __threadfence() (agent acq_rel) on both sides gives cross-XCD visibility
// of plain global stores (wbl2 before arrive, inv after release).
__device__ __forceinline__ void bar_sync(unsigned* ctr, unsigned target){
    __syncthreads();
    if (threadIdx.x == 0){
        __threadfence();
        __hip_atomic_fetch_add(ctr, 1u, __ATOMIC_RELAXED, __HIP_MEMORY_SCOPE_AGENT);
        while (__hip_atomic_load(ctr, __ATOMIC_RELAXED, __HIP_MEMORY_SCOPE_AGENT) < target)
            __builtin_amdgcn_s_sleep(2);
        __threadfence();
    }
    __syncthreads();
}

// ---------------------------------------------------------------------------
// Input projection: xp[row][h] = sum_i x[row][i]*lin_w[h][i] + lin_b[h], bf16 out
// ---------------------------------------------------------------------------
__global__ __launch_bounds__(256) void k_xp(const float* __restrict__ x,
                                            const float* __restrict__ lin_w,
                                            const float* __restrict__ lin_b,
                                            u16* __restrict__ xp)
{
    __shared__ float xl[16][128];
    const int rowbase = blockIdx.x * 16;
    const int t = threadIdx.x;
    for (int idx = t; idx < 16*128; idx += 256) {
        int r = idx >> 7, i = idx & 127;
        xl[r][i] = x[(rowbase + r)*128 + i];
    }
    __syncthreads();
    const int c0 = t;
    float acc0[16], acc1[16];
    #pragma unroll
    for (int r=0;r<16;r++){ acc0[r]=0.f; acc1[r]=0.f; }
    for (int k=0;k<128;k++){
        float w0 = lin_w[c0*128+k];
        float w1 = lin_w[(c0+256)*128+k];
        #pragma unroll
        for (int r=0;r<16;r++){
            float xv = xl[r][k];
            acc0[r] += xv*w0;
            acc1[r] += xv*w1;
        }
    }
    float b0 = lin_b[c0], b1 = lin_b[c0+256];
    #pragma unroll
    for (int r=0;r<16;r++){
        xp[(rowbase+r)*512 + c0]       = f2bf(acc0[r] + b0);
        xp[(rowbase+r)*512 + c0 + 256] = f2bf(acc1[r] + b1);
    }
}

// fp32 -> bf16 bulk convert (n multiple of 4)
__global__ __launch_bounds__(256) void k_cvt(const float* __restrict__ src,
                                             u16* __restrict__ dst, int n)
{
    int i = (blockIdx.x*256 + threadIdx.x)*4;
    if (i < n){
        float4 v = *reinterpret_cast<const float4*>(src + i);
        ushort4 o;
        o.x = f2bf(v.x); o.y = f2bf(v.y); o.z = f2bf(v.z); o.w = f2bf(v.w);
        *reinterpret_cast<ushort4*>(dst + i) = o;
    }
}

// ---------------------------------------------------------------------------
// Persistent cooperative recurrent kernel. 256 blocks x 256 threads.
// U lives permanently in LDS: block (tile=blk>>1, khalf=blk&1) holds
// U rows [l*2048+obase .. +64) x K-half [khalf*1024 .. +1024), XOR-swizzled.
// Per step: A (gh/hx/inp0) -> gbar -> B (GU partials, MFMA from LDS-U)
// -> gbar -> C x4 layers on 16 blocks with 16-block mini-barriers -> gbar.
// ---------------------------------------------------------------------------
__global__ __launch_bounds__(256, 1) void k_rnn(
    const u16*  __restrict__ xp,      // [32768][512] bf16
    const u16*  __restrict__ Wb,      // [4][2048][512] bf16
    const float* __restrict__ U,      // [4][2048][2048] fp32 (read once into LDS)
    const float* __restrict__ Gp,     // [4][512]
    const float* __restrict__ mask_u, // [4][32][512]
    const float* __restrict__ mask_w, // [4][32][512]
    const float* __restrict__ h0,
    const float* __restrict__ c0,
    float* __restrict__ h,            // [4][32][512] ws
    float* __restrict__ c,            // [4][32][512] ws
    u16*  __restrict__ hx,            // [32][2048] bf16 ws
    u16*  __restrict__ inp,           // [2][32][512] bf16 ws (layer-parity dbuf)
    float* __restrict__ GU,           // [2][4][32][2048] ws (K-half partials)
    unsigned* __restrict__ bars,      // [0]=grid ctr, [1]=cbar ctr (memset 0)
    float* __restrict__ out)          // d_out: hT | cT | gates[l][b][t]
{
    extern __shared__ char lds_raw[];
    u16*   Ulds = (u16*)lds_raw;                 // [64][1024] swizzled = 128KB
    float* red  = (float*)(lds_raw + 131072);    // 4096 floats = 16KB

    const int blk  = blockIdx.x;
    const int tid  = threadIdx.x;
    const int lane = tid & 63;
    const int wave = tid >> 6;

    const int tile  = blk >> 1;            // 0..127
    const int khalf = blk & 1;
    const int l_b   = tile >> 5;           // layer of U slice
    const int obase = (tile & 31) * 64;    // output-col base of U slice

    // ---- init state ----
    {
        int idx = blk*256 + tid;           // 65536 threads cover [4][32][512]
        h[idx] = h0[idx];
        c[idx] = c0[idx];
    }

    // ---- preload U slice into LDS (swizzled bf16) ----
    {
        const float* ubase = U + ((size_t)(l_b*2048 + obase))*2048 + khalf*1024;
        for (int it = 0; it < 32; ++it){
            int idx = it*256 + tid;        // 0..8191 = 64 rows x 128 chunks
            int r  = idx >> 7;
            int cc = idx & 127;
            const float* src = ubase + (size_t)r*2048 + cc*8;
            float4 f0 = *reinterpret_cast<const float4*>(src);
            float4 f1 = *reinterpret_cast<const float4*>(src + 4);
            union { bf16x8 v; u16 s[8]; } uu;
            uu.s[0]=f2bf(f0.x); uu.s[1]=f2bf(f0.y); uu.s[2]=f2bf(f0.z); uu.s[3]=f2bf(f0.w);
            uu.s[4]=f2bf(f1.x); uu.s[5]=f2bf(f1.y); uu.s[6]=f2bf(f1.z); uu.s[7]=f2bf(f1.w);
            int byte = r*2048 + ((cc*16) ^ ((r & 31) << 4));
            *reinterpret_cast<bf16x8*>(lds_raw + byte) = uu.v;
        }
    }

    unsigned ep  = 1;
    unsigned cep = 0;
    bar_sync(bars, 256u*ep);               // init + preload done

    const bool is_c = (blk < 128) && ((blk & 7) == 0);   // 16 C-blocks, all on XCD0
    const int  cidx  = blk >> 3;
    const int  hbase = cidx * 32;

    for (int t = 0; t < TT; ++t){
        // ---------------- Phase A ----------------
        if (blk < 128){
            int l = blk >> 5, b = blk & 31;
            const float* hp = h      + (l*32+b)*512;
            const float* mp = mask_u + (l*32+b)*512;
            const float* gp = Gp     + l*512;
            float hm0 = hp[tid]     * mp[tid];
            float hm1 = hp[tid+256] * mp[tid+256];
            float p = hm0*gp[tid] + hm1*gp[tid+256];
            #pragma unroll
            for (int off=32; off>0; off>>=1) p += __shfl_down(p, off);
            if (lane==0) red[wave] = p;
            __syncthreads();
            if (tid==0){
                float s  = red[0]+red[1]+red[2]+red[3];
                float gh = sigf(s);
                red[4] = gh;
                out[131072 + (l*32+b)*1024 + t] = gh;     // gates[l][b][t]
            }
            __syncthreads();
            float gh = red[4];
            u16* hxp = hx + b*2048 + l*512;
            hxp[tid]     = f2bf(gh*hm0);
            hxp[tid+256] = f2bf(gh*hm1);
        } else if (blk < 144){
            // inp0 = xp[t] * mask_w[0]
            int base = (blk-128)*1024 + tid;
            #pragma unroll
            for (int r=0;r<4;r++){
                int idx = base + r*256;
                int b = idx >> 9, k = idx & 511;
                float xv = bf2f(xp[(t*32+b)*512 + k]);
                inp[b*512 + k] = f2bf(xv * mask_w[b*512 + k]);
            }
        }
        ep++; bar_sync(bars, 256u*ep);

        // ---------------- Phase B: GU[khalf] partial = hx(Khalf) @ Uslice^T ----
        {
            const int kofs = ((lane>>5)<<3);                 // 0 or 8
            const u16* arow = hx + (lane&31)*2048 + khalf*1024 + wave*256 + kofs;
            const int  rrow = lane & 31;
            const int  swz  = rrow << 4;
            const int  cbase = (wave*256 + kofs) * 2;
            f32x16 acc0 = {}, acc1 = {};
            #pragma unroll 8
            for (int m=0; m<16; ++m){
                bf16x8 a  = *reinterpret_cast<const bf16x8*>(arow + m*16);
                int colb  = (cbase + m*32) ^ swz;
                bf16x8 b0 = *reinterpret_cast<const bf16x8*>(lds_raw + rrow*2048 + colb);
                bf16x8 b1 = *reinterpret_cast<const bf16x8*>(lds_raw + (32+rrow)*2048 + colb);
                acc0 = __builtin_amdgcn_mfma_f32_32x32x16_bf16(a, b0, acc0, 0, 0, 0);
                acc1 = __builtin_amdgcn_mfma_f32_32x32x16_bf16(a, b1, acc1, 0, 0, 0);
            }
            // cross-wave reduce: red[w2][c][r*64+lane], w2 = wave&1 after fold
            if (wave >= 2){
                #pragma unroll
                for (int r=0;r<16;r++){
                    red[(wave-2)*2048 +        r*64 + lane] = acc0[r];
                    red[(wave-2)*2048 + 1024 + r*64 + lane] = acc1[r];
                }
            }
            __syncthreads();
            if (wave < 2){
                #pragma unroll
                for (int r=0;r<16;r++){
                    red[wave*2048 +        r*64 + lane] += acc0[r];
                    red[wave*2048 + 1024 + r*64 + lane] += acc1[r];
                }
            }
            __syncthreads();
            for (int pos = tid; pos < 2048; pos += 256){
                float s = red[pos] + red[2048 + pos];
                int cc  = pos >> 10;
                int rem = pos & 1023;
                int r   = rem >> 6, ln = rem & 63;
                int row = (r&3) + 8*(r>>2) + 4*(ln>>5);       // batch index
                int col = obase + cc*32 + (ln&31);            // output index
                GU[khalf*262144 + (l_b*32 + row)*2048 + col] = s;
            }
        }
        ep++; bar_sync(bars, 256u*ep);

        // ---------------- Phase C: layer chain on 16 blocks ----------------
        for (int i=0; i<NLAYERS; ++i){
            if (is_c){
                const int o = wave*512 + hbase + (lane&31);    // gate-row in [0,2048)
                const int kofs = ((lane>>5)<<3);
                const u16* wrow  = Wb  + ((size_t)(i*2048 + o))*512 + kofs;
                const u16* arow2 = inp + (i&1)*16384 + (lane&31)*512 + kofs;
                f32x16 acc = {}, accB = {};
                #pragma unroll 4
                for (int m=0; m<32; m+=2){
                    bf16x8 a0 = *reinterpret_cast<const bf16x8*>(arow2 + m*16);
                    bf16x8 w0 = *reinterpret_cast<const bf16x8*>(wrow  + m*16);
                    bf16x8 a1 = *reinterpret_cast<const bf16x8*>(arow2 + (m+1)*16);
                    bf16x8 w1 = *reinterpret_cast<const bf16x8*>(wrow  + (m+1)*16);
                    acc  = __builtin_amdgcn_mfma_f32_32x32x16_bf16(a0, w0, acc,  0, 0, 0);
                    accB = __builtin_amdgcn_mfma_f32_32x32x16_bf16(a1, w1, accB, 0, 0, 0);
                }
                #pragma unroll
                for (int r=0;r<16;r++){
                    int row = (r&3) + 8*(r>>2) + 4*(lane>>5);
                    float g = GU[(i*32+row)*2048 + o] + GU[262144 + (i*32+row)*2048 + o];
                    red[wave*1024 + r*64 + lane] = acc[r] + accB[r] + g;
                }
                __syncthreads();
                for (int pos = tid; pos < 1024; pos += 256){
                    int r = pos >> 6, ln = pos & 63;
                    int b  = (r&3) + 8*(r>>2) + 4*(ln>>5);
                    int hh = hbase + (ln&31);
                    float ii = red[pos];
                    float ff = red[1024+pos];
                    float gg = red[2048+pos];
                    float oo = red[3072+pos];
                    int ci = (i*32+b)*512 + hh;
                    float cy = sigf(ff)*c[ci] + sigf(ii)*tanhf(gg);
                    float hy = sigf(oo)*tanhf(cy);
                    c[ci] = cy;
                    h[ci] = hy;
                    if (i < 3)
                        inp[((i+1)&1)*16384 + b*512 + hh] =
                            f2bf(hy * mask_w[(i+1)*16384 + b*512 + hh]);
                }
            }
            if (i < 3 && is_c){ cep++; bar_sync(bars+1, 16u*cep); }
            else if (i < 3)   { cep++; }
        }
        ep++; bar_sync(bars, 256u*ep);
    }

    // final hT, cT
    {
        int idx = blk*256 + tid;
        out[idx]         = h[idx];
        out[65536 + idx] = c[idx];
    }
}

// ---------------------------------------------------------------------------
extern "C" void kernel_launch(void* const* d_in, const int* in_sizes, int n_in,
                              void* d_out, int out_size, void* d_ws, size_t ws_size,
                              hipStream_t stream)
{
    const float* x      = (const float*)d_in[0];
    const float* lin_w  = (const float*)d_in[1];
    const float* lin_b  = (const float*)d_in[2];
    const float* W      = (const float*)d_in[3];
    const float* U      = (const float*)d_in[4];
    const float* Gp     = (const float*)d_in[5];
    const float* mask_u = (const float*)d_in[6];
    const float* mask_w = (const float*)d_in[7];
    const float* h0     = (const float*)d_in[8];
    const float* c0     = (const float*)d_in[9];
    float* out = (float*)d_out;

    char* ws = (char*)d_ws;
    size_t off = 0;
    auto alloc = [&](size_t bytes) -> void* {
        void* p = ws + off;
        off = (off + bytes + 255) & ~(size_t)255;
        return p;
    };
    unsigned* bars = (unsigned*)alloc(256);
    u16*   xp  = (u16*)  alloc(32768ull*512*2);       // 33.6 MB
    u16*   Wb  = (u16*)  alloc(4ull*2048*512*2);      //  8.4 MB
    float* h   = (float*)alloc(65536ull*4);
    float* c   = (float*)alloc(65536ull*4);
    u16*   hx  = (u16*)  alloc(32ull*2048*2);
    u16*   inp = (u16*)  alloc(2ull*32*512*2);
    float* GU  = (float*)alloc(2ull*4*32*2048*4);     //  2 MB (K-half partials)

    hipMemsetAsync(bars, 0, 256, stream);
    hipLaunchKernelGGL(k_xp,  dim3(2048), dim3(256), 0, stream, x, lin_w, lin_b, xp);
    hipLaunchKernelGGL(k_cvt, dim3(4096), dim3(256), 0, stream, W, Wb, 4194304);

    hipFuncSetAttribute(reinterpret_cast<const void*>(k_rnn),
                        hipFuncAttributeMaxDynamicSharedMemorySize, 147456);

    void* args[] = { &xp, &Wb, &U, &Gp, &mask_u, &mask_w, &h0, &c0,
                     &h, &c, &hx, &inp, &GU, &bars, &out };
    hipLaunchCooperativeKernel(reinterpret_cast<void*>(k_rnn),
                               dim3(256), dim3(256), args, 147456, stream);
}